// Round 2
// baseline (558.945 us; speedup 1.0000x reference)
//
#include <hip/hip_runtime.h>

// StructuralLoss: windowed ZNCC loss, sigma=4 -> w=2 (4x4 box windows).
// Register-streaming, no LDS. Each thread owns 4 output columns, streams
// RY=16 rows. One-step software prefetch: loads issued in step k are
// consumed in step k+1. Ring phases compile-time via template<int K>.
// Per-block partial sums -> ws[]; finalize kernel reduces (no atomics).

#define HH 4096
#define WW 4096
constexpr int RY = 16;            // output rows per thread (grid.y = 256 -> 1024 blocks = 4/CU)
constexpr float EPf = 1e-12f;     // clamp floor (ref uses 1e-20; variance ~0.1, no effect)

struct ThreadState {
    // raw row ring: [slot][10 cols] = raw cols j0-2 .. j0+7
    float A[4][10];
    float B[4][10];
    // prefetch registers (next raw row)
    float PA[10], PB[10];
    // H rings: [slot][4 output cols]
    float Hii[4][4], Hjj[4][4], Hij[4][4];
    float cmask[7];               // c-column validity (cols j0-1 .. j0+5)
    float acc;
};

__device__ __forceinline__ float4 zero4() { return make_float4(0.f, 0.f, 0.f, 0.f); }

// Load raw row t (both images) into P1/P2 (10 floats: cols j0-2..j0+7).
__device__ __forceinline__ void load_P(float (&P1)[10], float (&P2)[10],
                                       const float* __restrict__ i1,
                                       const float* __restrict__ i2,
                                       int t, int j0, bool okL, bool okR, bool live) {
    float4 a0, a1, a2, b0, b1, b2;
    if (live && t >= 0 && t < HH) {               // wave-uniform branch
        const float* p1 = i1 + (long)t * WW + j0;
        const float* p2 = i2 + (long)t * WW + j0;
        a0 = okL ? *(const float4*)(p1 - 4) : zero4();
        a1 = *(const float4*)(p1);
        a2 = okR ? *(const float4*)(p1 + 4) : zero4();
        b0 = okL ? *(const float4*)(p2 - 4) : zero4();
        b1 = *(const float4*)(p2);
        b2 = okR ? *(const float4*)(p2 + 4) : zero4();
    } else {
        a0 = a1 = a2 = b0 = b1 = b2 = zero4();
    }
    P1[0] = a0.z; P1[1] = a0.w;
    P1[2] = a1.x; P1[3] = a1.y; P1[4] = a1.z; P1[5] = a1.w;
    P1[6] = a2.x; P1[7] = a2.y; P1[8] = a2.z; P1[9] = a2.w;
    P2[0] = b0.z; P2[1] = b0.w;
    P2[2] = b1.x; P2[3] = b1.y; P2[4] = b1.z; P2[5] = b1.w;
    P2[6] = b2.x; P2[7] = b2.y; P2[8] = b2.z; P2[9] = b2.w;
}

template <int K>
__device__ __forceinline__ void step(ThreadState& st,
                                     const float* __restrict__ i1,
                                     const float* __restrict__ i2,
                                     int rrb, int y0, int j0, bool okL, bool okR) {
    const int rr = rrb + K;        // iteration index 0..RY+2
    const int r  = y0 - 1 + rr;    // c-row produced this iteration

    // commit prefetched raw row r+2 into ring slot K (waits on last step's load)
#pragma unroll
    for (int m = 0; m < 10; ++m) { st.A[K][m] = st.PA[m]; st.B[K][m] = st.PB[m]; }

    // issue prefetch of raw row r+3 for the NEXT step (consumed one step later)
    load_P(st.PA, st.PB, i1, i2, r + 3, j0, okL, okR, rr <= RY + 1);

    // vertical 4-sums over the ring (raw rows r-1..r+2), all 10 cols
    float vs1[10], vs2[10];
#pragma unroll
    for (int m = 0; m < 10; ++m) {
        vs1[m] = st.A[0][m] + st.A[1][m] + st.A[2][m] + st.A[3][m];
        vs2[m] = st.B[0][m] + st.B[1][m] + st.B[2][m] + st.B[3][m];
    }

    constexpr int CS = (K + 2) & 3;  // slot holding raw row r (center)
    const float rmask = (r >= 0 && r < HH) ? 1.f : 0.f;

    // centered values at 7 c-columns (global col j0-1+k)
    float c1[7], c2[7];
#pragma unroll
    for (int k = 0; k < 7; ++k) {
        float mu1 = (vs1[k] + vs1[k + 1] + vs1[k + 2] + vs1[k + 3]) * 0.0625f;
        float mu2 = (vs2[k] + vs2[k + 1] + vs2[k + 2] + vs2[k + 3]) * 0.0625f;
        float msk = rmask * st.cmask[k];
        c1[k] = (st.A[CS][k + 1] - mu1) * msk;
        c2[k] = (st.B[CS][k + 1] - mu2) * msk;
    }

    // horizontal 4-sums of products for the 4 output columns -> H ring slot K
#pragma unroll
    for (int q = 0; q < 4; ++q) {
        float hii = 0.f, hjj = 0.f, hij = 0.f;
#pragma unroll
        for (int s = 0; s < 4; ++s) {
            float a = c1[q + s], b = c2[q + s];
            hii += a * a;
            hjj += b * b;
            hij += a * b;
        }
        st.Hii[K][q] = hii; st.Hjj[K][q] = hjj; st.Hij[K][q] = hij;
    }

    // emit output row i = r-2 once H ring holds c-rows i-1..i+2
    if (rr >= 3) {                 // wave-uniform; rr <= RY+2 by construction
#pragma unroll
        for (int q = 0; q < 4; ++q) {
            float sii = st.Hii[0][q] + st.Hii[1][q] + st.Hii[2][q] + st.Hii[3][q];
            float sjj = st.Hjj[0][q] + st.Hjj[1][q] + st.Hjj[2][q] + st.Hjj[3][q];
            float sij = st.Hij[0][q] + st.Hij[1][q] + st.Hij[2][q] + st.Hij[3][q];
            sii = fmaxf(sii, EPf);
            sjj = fmaxf(sjj, EPf);
            float L = sij * rsqrtf(sii * sjj);
            L = fmaxf(L, -1.f);
            st.acc += 1.f - L;
        }
    }
}

__global__ __launch_bounds__(256, 4) void xcorr_loss_kernel(
    const float* __restrict__ img1, const float* __restrict__ img2,
    float* __restrict__ partial) {
    const int tcol = blockIdx.x * blockDim.x + threadIdx.x;  // thread col-group
    const int j0   = tcol * 4;
    const int y0   = blockIdx.y * RY;

    ThreadState st;
    st.acc = 0.f;
#pragma unroll
    for (int k = 0; k < 7; ++k) {
        int cc = j0 - 1 + k;
        st.cmask[k] = (cc >= 0 && cc < WW) ? 1.f : 0.f;
    }
    const bool okL = (j0 - 4) >= 0;
    const bool okR = (j0 + 7) < WW;

    // prime: rows y0-2, y0-1, y0 into ring slots 1,2,3; prefetch row y0+1
    load_P(st.A[1], st.B[1], img1, img2, y0 - 2, j0, okL, okR, true);
    load_P(st.A[2], st.B[2], img1, img2, y0 - 1, j0, okL, okR, true);
    load_P(st.A[3], st.B[3], img1, img2, y0,     j0, okL, okR, true);
    load_P(st.PA,   st.PB,   img1, img2, y0 + 1, j0, okL, okR, true);

    // RY+3 = 19 steps: 4 groups of 4 + 3-step tail
    for (int o = 0; o < 4; ++o) {
        const int rrb = o * 4;
        step<0>(st, img1, img2, rrb, y0, j0, okL, okR);
        step<1>(st, img1, img2, rrb, y0, j0, okL, okR);
        step<2>(st, img1, img2, rrb, y0, j0, okL, okR);
        step<3>(st, img1, img2, rrb, y0, j0, okL, okR);
    }
    step<0>(st, img1, img2, 16, y0, j0, okL, okR);
    step<1>(st, img1, img2, 16, y0, j0, okL, okR);
    step<2>(st, img1, img2, 16, y0, j0, okL, okR);

    // wave (64) shuffle reduce, then LDS across the block's 4 waves
    float wsum = st.acc;
#pragma unroll
    for (int off = 32; off > 0; off >>= 1)
        wsum += __shfl_down(wsum, off, 64);

    __shared__ float red[4];
    const int lane = threadIdx.x & 63;
    const int wid  = threadIdx.x >> 6;
    if (lane == 0) red[wid] = wsum;
    __syncthreads();
    if (threadIdx.x == 0) {
        float bsum = red[0] + red[1] + red[2] + red[3];
        partial[blockIdx.y * gridDim.x + blockIdx.x] = bsum;
    }
}

__global__ __launch_bounds__(256) void finalize_kernel(
    const float* __restrict__ partial, int nb, float* __restrict__ out) {
    double s = 0.0;
    for (int i = threadIdx.x; i < nb; i += 256)
        s += (double)partial[i];
#pragma unroll
    for (int off = 32; off > 0; off >>= 1)
        s += __shfl_down(s, off, 64);
    __shared__ double red[4];
    const int lane = threadIdx.x & 63;
    const int wid  = threadIdx.x >> 6;
    if (lane == 0) red[wid] = s;
    __syncthreads();
    if (threadIdx.x == 0) {
        double tot = red[0] + red[1] + red[2] + red[3];
        double mean = tot / ((double)HH * (double)WW);
        out[0] = (float)mean;
        out[1] = (float)mean;
    }
}

extern "C" void kernel_launch(void* const* d_in, const int* in_sizes, int n_in,
                              void* d_out, int out_size, void* d_ws, size_t ws_size,
                              hipStream_t stream) {
    const float* img1 = (const float*)d_in[0];  // outputs
    const float* img2 = (const float*)d_in[1];  // labels
    float* partial = (float*)d_ws;              // 1024 floats

    dim3 grid(WW / (256 * 4), HH / RY);         // (4, 256) = 1024 blocks
    xcorr_loss_kernel<<<grid, dim3(256), 0, stream>>>(img1, img2, partial);
    finalize_kernel<<<1, 256, 0, stream>>>(partial, grid.x * grid.y, (float*)d_out);
}

// Round 3
// 208.531 us; speedup vs baseline: 2.6804x; 2.6804x over previous
//
#include <hip/hip_runtime.h>

// StructuralLoss: windowed ZNCC loss, sigma=4 -> w=2 (4x4 box windows).
// Register-streaming, no LDS. Each thread owns 4 output columns, streams
// RY=16 rows (grid = 1024 blocks = 4 blocks/CU = 16 waves/CU).
// NOTE: do NOT force min-waves in __launch_bounds__ — with ~100 live
// floats/thread it caps VGPR=64 and spills everything (R2: 1.6 GB scratch
// traffic, 460 us). Natural VGPR ~108 <= 128 already gives 4 waves/EU.

#define HH 4096
#define WW 4096
constexpr int RY = 16;            // output rows per thread
constexpr float EPf = 1e-12f;     // clamp floor (ref 1e-20; typical variance ~0.1)

struct ThreadState {
    // raw row ring: [slot][10 cols] = raw cols j0-2 .. j0+7
    float A[4][10];
    float B[4][10];
    // H rings: [slot][4 output cols]
    float Hii[4][4], Hjj[4][4], Hij[4][4];
    float cmask[7];               // c-column validity (cols j0-1 .. j0+5)
    float acc;
};

__device__ __forceinline__ float4 zero4() { return make_float4(0.f, 0.f, 0.f, 0.f); }

// Load raw row t (both images) into ring slot SLOT (10 floats: cols j0-2..j0+7).
template <int SLOT>
__device__ __forceinline__ void load_row(ThreadState& st,
                                         const float* __restrict__ i1,
                                         const float* __restrict__ i2,
                                         int t, int j0, bool okL, bool okR) {
    float4 a0, a1, a2, b0, b1, b2;
    if (t >= 0 && t < HH) {                       // wave-uniform branch
        const float* p1 = i1 + (long)t * WW + j0;
        const float* p2 = i2 + (long)t * WW + j0;
        a0 = okL ? *(const float4*)(p1 - 4) : zero4();
        a1 = *(const float4*)(p1);
        a2 = okR ? *(const float4*)(p1 + 4) : zero4();
        b0 = okL ? *(const float4*)(p2 - 4) : zero4();
        b1 = *(const float4*)(p2);
        b2 = okR ? *(const float4*)(p2 + 4) : zero4();
    } else {
        a0 = a1 = a2 = b0 = b1 = b2 = zero4();
    }
    st.A[SLOT][0] = a0.z; st.A[SLOT][1] = a0.w;
    st.A[SLOT][2] = a1.x; st.A[SLOT][3] = a1.y; st.A[SLOT][4] = a1.z; st.A[SLOT][5] = a1.w;
    st.A[SLOT][6] = a2.x; st.A[SLOT][7] = a2.y; st.A[SLOT][8] = a2.z; st.A[SLOT][9] = a2.w;
    st.B[SLOT][0] = b0.z; st.B[SLOT][1] = b0.w;
    st.B[SLOT][2] = b1.x; st.B[SLOT][3] = b1.y; st.B[SLOT][4] = b1.z; st.B[SLOT][5] = b1.w;
    st.B[SLOT][6] = b2.x; st.B[SLOT][7] = b2.y; st.B[SLOT][8] = b2.z; st.B[SLOT][9] = b2.w;
}

template <int K>
__device__ __forceinline__ void step(ThreadState& st,
                                     const float* __restrict__ i1,
                                     const float* __restrict__ i2,
                                     int rrb, int y0, int j0, bool okL, bool okR) {
    const int rr = rrb + K;        // iteration index 0..RY+2
    const int r  = y0 - 1 + rr;    // c-row produced this iteration

    // load raw row r+2 into ring slot K (oldest slot)
    load_row<K>(st, i1, i2, r + 2, j0, okL, okR);

    // vertical 4-sums over the ring (raw rows r-1..r+2), all 10 cols
    float vs1[10], vs2[10];
#pragma unroll
    for (int m = 0; m < 10; ++m) {
        vs1[m] = st.A[0][m] + st.A[1][m] + st.A[2][m] + st.A[3][m];
        vs2[m] = st.B[0][m] + st.B[1][m] + st.B[2][m] + st.B[3][m];
    }

    constexpr int CS = (K + 2) & 3;  // slot holding raw row r (center)
    const float rmask = (r >= 0 && r < HH) ? 1.f : 0.f;

    // centered values at 7 c-columns (global col j0-1+k)
    float c1[7], c2[7];
#pragma unroll
    for (int k = 0; k < 7; ++k) {
        float mu1 = (vs1[k] + vs1[k + 1] + vs1[k + 2] + vs1[k + 3]) * 0.0625f;
        float mu2 = (vs2[k] + vs2[k + 1] + vs2[k + 2] + vs2[k + 3]) * 0.0625f;
        float msk = rmask * st.cmask[k];
        c1[k] = (st.A[CS][k + 1] - mu1) * msk;
        c2[k] = (st.B[CS][k + 1] - mu2) * msk;
    }

    // horizontal 4-sums of products for the 4 output columns -> H ring slot K
#pragma unroll
    for (int q = 0; q < 4; ++q) {
        float hii = 0.f, hjj = 0.f, hij = 0.f;
#pragma unroll
        for (int s = 0; s < 4; ++s) {
            float a = c1[q + s], b = c2[q + s];
            hii += a * a;
            hjj += b * b;
            hij += a * b;
        }
        st.Hii[K][q] = hii; st.Hjj[K][q] = hjj; st.Hij[K][q] = hij;
    }

    // emit output row i = r-2 once H ring holds c-rows i-1..i+2
    if (rr >= 3) {                 // wave-uniform; rr <= RY+2 by construction
#pragma unroll
        for (int q = 0; q < 4; ++q) {
            float sii = st.Hii[0][q] + st.Hii[1][q] + st.Hii[2][q] + st.Hii[3][q];
            float sjj = st.Hjj[0][q] + st.Hjj[1][q] + st.Hjj[2][q] + st.Hjj[3][q];
            float sij = st.Hij[0][q] + st.Hij[1][q] + st.Hij[2][q] + st.Hij[3][q];
            sii = fmaxf(sii, EPf);
            sjj = fmaxf(sjj, EPf);
            float L = sij * rsqrtf(sii * sjj);
            L = fmaxf(L, -1.f);
            st.acc += 1.f - L;
        }
    }
}

__global__ __launch_bounds__(256) void xcorr_loss_kernel(
    const float* __restrict__ img1, const float* __restrict__ img2,
    float* __restrict__ partial) {
    const int tcol = blockIdx.x * blockDim.x + threadIdx.x;  // thread col-group
    const int j0   = tcol * 4;
    const int y0   = blockIdx.y * RY;

    ThreadState st;
    st.acc = 0.f;
#pragma unroll
    for (int k = 0; k < 7; ++k) {
        int cc = j0 - 1 + k;
        st.cmask[k] = (cc >= 0 && cc < WW) ? 1.f : 0.f;
    }
    const bool okL = (j0 - 4) >= 0;
    const bool okR = (j0 + 7) < WW;

    // prime: raw rows y0-2, y0-1, y0 into ring slots 1,2,3
    load_row<1>(st, img1, img2, y0 - 2, j0, okL, okR);
    load_row<2>(st, img1, img2, y0 - 1, j0, okL, okR);
    load_row<3>(st, img1, img2, y0,     j0, okL, okR);

    // RY+3 = 19 steps: 4 groups of 4 + 3-step tail
    for (int o = 0; o < 4; ++o) {
        const int rrb = o * 4;
        step<0>(st, img1, img2, rrb, y0, j0, okL, okR);
        step<1>(st, img1, img2, rrb, y0, j0, okL, okR);
        step<2>(st, img1, img2, rrb, y0, j0, okL, okR);
        step<3>(st, img1, img2, rrb, y0, j0, okL, okR);
    }
    step<0>(st, img1, img2, 16, y0, j0, okL, okR);
    step<1>(st, img1, img2, 16, y0, j0, okL, okR);
    step<2>(st, img1, img2, 16, y0, j0, okL, okR);

    // wave (64) shuffle reduce, then LDS across the block's 4 waves
    float wsum = st.acc;
#pragma unroll
    for (int off = 32; off > 0; off >>= 1)
        wsum += __shfl_down(wsum, off, 64);

    __shared__ float red[4];
    const int lane = threadIdx.x & 63;
    const int wid  = threadIdx.x >> 6;
    if (lane == 0) red[wid] = wsum;
    __syncthreads();
    if (threadIdx.x == 0) {
        float bsum = red[0] + red[1] + red[2] + red[3];
        partial[blockIdx.y * gridDim.x + blockIdx.x] = bsum;
    }
}

__global__ __launch_bounds__(256) void finalize_kernel(
    const float* __restrict__ partial, int nb, float* __restrict__ out) {
    double s = 0.0;
    for (int i = threadIdx.x; i < nb; i += 256)
        s += (double)partial[i];
#pragma unroll
    for (int off = 32; off > 0; off >>= 1)
        s += __shfl_down(s, off, 64);
    __shared__ double red[4];
    const int lane = threadIdx.x & 63;
    const int wid  = threadIdx.x >> 6;
    if (lane == 0) red[wid] = s;
    __syncthreads();
    if (threadIdx.x == 0) {
        double tot = red[0] + red[1] + red[2] + red[3];
        double mean = tot / ((double)HH * (double)WW);
        out[0] = (float)mean;
        out[1] = (float)mean;
    }
}

extern "C" void kernel_launch(void* const* d_in, const int* in_sizes, int n_in,
                              void* d_out, int out_size, void* d_ws, size_t ws_size,
                              hipStream_t stream) {
    const float* img1 = (const float*)d_in[0];  // outputs
    const float* img2 = (const float*)d_in[1];  // labels
    float* partial = (float*)d_ws;              // 1024 floats

    dim3 grid(WW / (256 * 4), HH / RY);         // (4, 256) = 1024 blocks
    xcorr_loss_kernel<<<grid, dim3(256), 0, stream>>>(img1, img2, partial);
    finalize_kernel<<<1, 256, 0, stream>>>(partial, grid.x * grid.y, (float*)d_out);
}